// Round 7
// baseline (681.111 us; speedup 1.0000x reference)
//
#include <hip/hip_runtime.h>

// SNN 2-layer forward: s2 = (( (x@W1.T >=1) @ W2.T) >= 1)
// B=4096, IN=3136, FEAT=6272, OUT=500; x and s1 binary {0,1}.
// Exact 3-limb i8-MFMA GEMM (w = d0*2^-7+d1*2^-14+d2*2^-21+r, |r|<=2^-22,
// i32 MFMA accumulation exact, f64 Horner exact) + worst-case-safe sparse
// fp64 correction of all dots with |v_hat-1| <= K*2^-22.
//
// Round-15 == Round-14 resubmit (container infra failure, no verdict;
// same signature as R11's flake which passed on identical resubmit).
// R13 falsified LDS-BW (half the reads/MFMA, identical 258us).
// Cross-variant invariant: per-kt wall ~2050cy vs 878cy MFMA/SIMD in EVERY
// config (v6/v9/v10; 1 or 2 blk/CU; 1 or 3 kt/barrier) -> ~86cy/MFMA
// effective. The common factor: each wave's serial expand16 chain (~128cy
// VALU/kt) + A bit-loads run barrier-phase-locked in ALL waves at once, so
// VALU (42% busy) and MFMA (43%) never overlap. Fix: pre-expand x to i8 in
// GLOBAL (pack_x8, 12.8MB, fragment-major: per (kt,rowgrp,kk) 1KB slot,
// lane l bytes at l*16) -> fc1 A-operand = 1 coalesced dwordx4 load, zero
// loop VALU. Inner loop/kt/wave: 6 B ds_reads + 4 A loads (prefetched
// 1 kt ahead) + 12 MFMA. Block 256x64, wave 64x32, plain syncthreads dbuf
// (best tried), XCD swizzle kept.

namespace {
constexpr int kB = 4096;
constexpr int kIn = 3136;        // 49 chunks of 64
constexpr int kFeat = 6272;      // 98 chunks of 64
constexpr int kFeatWords = 196;  // u32 per s1 row
constexpr int kOut = 500;
constexpr size_t kPlane1 = (size_t)kFeat * kIn;
constexpr size_t kW1F = 3 * kPlane1;                 // 59,006,976 (4802*12288)
constexpr size_t kW2F = (size_t)784 * 12288;         // 9,633,792
constexpr size_t kS1Bytes = (size_t)kB * kFeatWords * 4;  // 3,211,264 (x2)
constexpr size_t kX8Bytes = (size_t)49 * 256 * 1024; // 12,845,056 (frag-major)
constexpr unsigned kCap1 = 1u << 20;
constexpr unsigned kCap2 = 1u << 16;
__device__ constexpr double kTau1 = 7.4769e-4;       // > 3136*2^-22
__device__ constexpr double kTau2 = 1.4955e-3;       // > 6272*2^-22
}  // namespace

typedef int v4i __attribute__((ext_vector_type(4)));
typedef int v16i __attribute__((ext_vector_type(16)));

__device__ __forceinline__ void gload_lds16(const void* g, void* l) {
  __builtin_amdgcn_global_load_lds((__attribute__((address_space(1))) void*)(g),
                                   (__attribute__((address_space(3))) void*)(l),
                                   16, 0, 0);
}

// 16 bits -> 16 i8 (byte i = bit i)  [used by fc2 only now]
__device__ __forceinline__ v4i expand16(unsigned b) {
  unsigned u0 = (((b      ) & 0xFu) * 0x204081u) & 0x01010101u;
  unsigned u1 = (((b >> 4 ) & 0xFu) * 0x204081u) & 0x01010101u;
  unsigned u2 = (((b >> 8 ) & 0xFu) * 0x204081u) & 0x01010101u;
  unsigned u3 = (((b >> 12) & 0xFu) * 0x204081u) & 0x01010101u;
  return (v4i){(int)u0, (int)u1, (int)u2, (int)u3};
}

// exact 3-digit signed base-128 split; |w - sum| <= 2^-22
__device__ __forceinline__ void split3(float w, signed char* d) {
  float c = rintf(w * 128.f);
  d[0] = (signed char)(int)c;
  float r = fmaf(c, -7.8125e-03f, w);
  c = rintf(r * 16384.f);
  d[1] = (signed char)(int)c;
  r = fmaf(c, -6.103515625e-05f, r);
  c = rintf(r * 2097152.f);
  d[2] = (signed char)(int)c;
}

// ---------------------------------------------------------------------------
// W1 -> fragment-major limbs: slot(fb,kt,j,g) = 1KB of 64 feats x 16 k-bytes.
// ---------------------------------------------------------------------------
__global__ __launch_bounds__(256) void conv_w1F(const float* __restrict__ W,
                                                signed char* __restrict__ F) {
  const int bx = blockIdx.x;               // fb*49 + kt, < 4802
  const int fb = bx / 49;
  const int kt = bx % 49;
  const int f = threadIdx.x & 63;
  const int g = threadIdx.x >> 6;
  const float* src = W + (size_t)(fb * 64 + f) * kIn + kt * 64 + g * 16;
  union { signed char c[16]; int4 v; } o[3];
#pragma unroll
  for (int q = 0; q < 4; ++q) {
    const float4 w = *(const float4*)(src + q * 4);
    signed char d[4][3];
    split3(w.x, d[0]); split3(w.y, d[1]); split3(w.z, d[2]); split3(w.w, d[3]);
#pragma unroll
    for (int e = 0; e < 4; ++e)
#pragma unroll
      for (int j = 0; j < 3; ++j) o[j].c[q * 4 + e] = d[e][j];
  }
#pragma unroll
  for (int j = 0; j < 3; ++j)
    *(int4*)(F + ((size_t)bx * 3 + j) * 4096 + g * 1024 + f * 16) = o[j].v;
}

// W2 (padded to 512 rows) -> fragment-major limbs, slots (fb<8, kt<98, j, g)
__global__ __launch_bounds__(256) void conv_w2F(const float* __restrict__ W,
                                                signed char* __restrict__ F) {
  const int bx = blockIdx.x;               // fb*98 + kt, < 784
  const int fb = bx / 98;
  const int kt = bx % 98;
  const int f = threadIdx.x & 63;
  const int g = threadIdx.x >> 6;
  const int feat = fb * 64 + f;
  union { signed char c[16]; int4 v; } o[3];
#pragma unroll
  for (int q = 0; q < 4; ++q) {
    float4 w = {0.f, 0.f, 0.f, 0.f};
    if (feat < kOut)
      w = *(const float4*)(W + (size_t)feat * kFeat + kt * 64 + g * 16 + q * 4);
    signed char d[4][3];
    split3(w.x, d[0]); split3(w.y, d[1]); split3(w.z, d[2]); split3(w.w, d[3]);
#pragma unroll
    for (int e = 0; e < 4; ++e)
#pragma unroll
      for (int j = 0; j < 3; ++j) o[j].c[q * 4 + e] = d[e][j];
  }
#pragma unroll
  for (int j = 0; j < 3; ++j)
    *(int4*)(F + ((size_t)bx * 3 + j) * 4096 + g * 1024 + f * 16) = o[j].v;
}

// x -> fragment-major expanded i8 bytes: slot (kt*256 + mgrp*2 + kk)*1024;
// lane l's 16 bytes at l*16 hold x[row = mgrp*32 + (l&31)]
// [k = kt*64 + kk*32 + (l>>5)*16 + j] as i8 0/1.
__global__ __launch_bounds__(256) void pack_x8(const float* __restrict__ X,
                                               signed char* __restrict__ xb8) {
  const int slot = blockIdx.x * 4 + (threadIdx.x >> 6);  // < 12544
  const int lane = threadIdx.x & 63;
  const int kk = slot & 1;
  const int mgrp = (slot >> 1) & 127;
  const int kt = slot >> 8;
  const int row = mgrp * 32 + (lane & 31);
  const int k0 = kt * 64 + kk * 32 + (lane >> 5) * 16;
  const float* src = X + (size_t)row * kIn + k0;
  union { signed char c[16]; int4 v; } o;
#pragma unroll
  for (int q = 0; q < 4; ++q) {
    const float4 w = *(const float4*)(src + q * 4);
    o.c[q * 4 + 0] = (w.x != 0.f) ? 1 : 0;
    o.c[q * 4 + 1] = (w.y != 0.f) ? 1 : 0;
    o.c[q * 4 + 2] = (w.z != 0.f) ? 1 : 0;
    o.c[q * 4 + 3] = (w.w != 0.f) ? 1 : 0;
  }
  *(int4*)(xb8 + (size_t)slot * 1024 + lane * 16) = o.v;
}

// ---------------------------------------------------------------------------
// FC1 v11: tile M=256,N=64,BK=64; 512 thr = 8 waves (4 waveM x 2 waveN),
// wave tile 64x32, acc[2][3] (96 AGPR). B via LDS dbuf (2x12KB, plain
// __syncthreads drain). A = pre-expanded bytes from xb8, 4 coalesced
// dwordx4 loads/kt/wave, register double-buffered (prefetch 1 kt ahead).
// Zero in-loop VALU expansion. launch_bounds(512,2). Grid (16, 98);
// XCD swizzle (1568 = 8*196).
// ---------------------------------------------------------------------------
__global__ __launch_bounds__(512, 2) void fc1_v11(
    const signed char* __restrict__ xb8, const signed char* __restrict__ w1lF,
    unsigned* __restrict__ s1b, unsigned* __restrict__ s1T,
    unsigned* __restrict__ cnt, unsigned* __restrict__ list) {
  __shared__ __align__(16) signed char lds[24576];  // 2 x 12 KB
  const int tid = threadIdx.x;
  const int lane = tid & 63;
  const int ln31 = lane & 31;
  const int half = lane >> 5;
  const int wv = tid >> 6;       // 0..7
  const int waveM = wv >> 1;     // 0..3 (64 rows each)
  const int waveN = wv & 1;      // 0..1

  // XCD swizzle: 1568 = 8*196 (bijective).
  const int lin = blockIdx.x + 16 * blockIdx.y;     // 0..1567
  const int sw = (lin & 7) * 196 + (lin >> 3);
  const int bx = sw >> 4;        // N-block (64 feats), 0..97
  const int bM = (sw & 15) * 256;

  // B staging: 12 slots/tile; wave wv stages slot wv, and wv+8 if wv<4
  const signed char* const gbase = w1lF + (size_t)bx * 49 * 12288;
  const bool has1 = (wv < 4);
  const unsigned sG0 = wv * 1024u + lane * 16u;
  const unsigned sL0 = wv * 1024u;
  const unsigned sG1 = (wv + 8) * 1024u + lane * 16u;
  const unsigned sL1 = (wv + 8) * 1024u;

  // A: fragment-major slots. gmgrp0 = first 32-row group of this wave.
  const int gmgrp0 = (bM >> 5) + waveM * 2;
  const signed char* apn =
      xb8 + ((size_t)gmgrp0 * 2) * 1024 + lane * 16u;  // kt=0 base
  const unsigned bfeat = (waveN * 32 + ln31) * 16u;

  v16i acc[2][3] = {};
  v4i c00, c01, c10, c11;  // A frags cur: (sub, kk)
  v4i n00, n01, n10, n11;  // A frags next kt

  // prologue: stage kt0 -> buf0; load A(kt0)
  gload_lds16(gbase + sG0, lds + sL0);
  if (has1) gload_lds16(gbase + sG1, lds + sL1);
  c00 = *(const v4i*)(apn);
  c01 = *(const v4i*)(apn + 1024);
  c10 = *(const v4i*)(apn + 2048);
  c11 = *(const v4i*)(apn + 3072);
  apn += 262144;                                 // -> kt=1 (256 KB/kt)
  const signed char* gstage = gbase + 12288;     // -> S(1)

  for (int kt = 0; kt < 49; ++kt) {
    __syncthreads();  // drains stage(kt) + A prefetch; prev compute done
    const int cb = (kt & 1) * 12288;
    if (kt < 48) {
      const int nb = ((kt + 1) & 1) * 12288;
      gload_lds16(gstage + sG0, lds + nb + sL0);
      if (has1) gload_lds16(gstage + sG1, lds + nb + sL1);
      gstage += 12288;
      n00 = *(const v4i*)(apn);
      n01 = *(const v4i*)(apn + 1024);
      n10 = *(const v4i*)(apn + 2048);
      n11 = *(const v4i*)(apn + 3072);
      apn += 262144;
    }
    // kk = 0
    {
      const unsigned gsel = half * 1024u;
      const v4i b0 = *(const v4i*)(lds + cb + 0 * 4096 + gsel + bfeat);
      const v4i b1 = *(const v4i*)(lds + cb + 1 * 4096 + gsel + bfeat);
      const v4i b2 = *(const v4i*)(lds + cb + 2 * 4096 + gsel + bfeat);
      acc[0][0] = __builtin_amdgcn_mfma_i32_32x32x32_i8(c00, b0, acc[0][0], 0, 0, 0);
      acc[0][1] = __builtin_amdgcn_mfma_i32_32x32x32_i8(c00, b1, acc[0][1], 0, 0, 0);
      acc[0][2] = __builtin_amdgcn_mfma_i32_32x32x32_i8(c00, b2, acc[0][2], 0, 0, 0);
      acc[1][0] = __builtin_amdgcn_mfma_i32_32x32x32_i8(c10, b0, acc[1][0], 0, 0, 0);
      acc[1][1] = __builtin_amdgcn_mfma_i32_32x32x32_i8(c10, b1, acc[1][1], 0, 0, 0);
      acc[1][2] = __builtin_amdgcn_mfma_i32_32x32x32_i8(c10, b2, acc[1][2], 0, 0, 0);
    }
    // kk = 1
    {
      const unsigned gsel = (2 + half) * 1024u;
      const v4i b0 = *(const v4i*)(lds + cb + 0 * 4096 + gsel + bfeat);
      const v4i b1 = *(const v4i*)(lds + cb + 1 * 4096 + gsel + bfeat);
      const v4i b2 = *(const v4i*)(lds + cb + 2 * 4096 + gsel + bfeat);
      acc[0][0] = __builtin_amdgcn_mfma_i32_32x32x32_i8(c01, b0, acc[0][0], 0, 0, 0);
      acc[0][1] = __builtin_amdgcn_mfma_i32_32x32x32_i8(c01, b1, acc[0][1], 0, 0, 0);
      acc[0][2] = __builtin_amdgcn_mfma_i32_32x32x32_i8(c01, b2, acc[0][2], 0, 0, 0);
      acc[1][0] = __builtin_amdgcn_mfma_i32_32x32x32_i8(c11, b0, acc[1][0], 0, 0, 0);
      acc[1][1] = __builtin_amdgcn_mfma_i32_32x32x32_i8(c11, b1, acc[1][1], 0, 0, 0);
      acc[1][2] = __builtin_amdgcn_mfma_i32_32x32x32_i8(c11, b2, acc[1][2], 0, 0, 0);
    }
    c00 = n00; c01 = n01; c10 = n10; c11 = n11;
  }

  const double s7 = 0.0078125;
  const int word = bx * 2 + waveN;
  const int fcol = word * 32 + ln31;
#pragma unroll
  for (int sub = 0; sub < 2; ++sub) {
#pragma unroll
    for (int t = 0; t < 16; ++t) {
      double v = (double)acc[sub][2][t];
      v = v * s7 + (double)acc[sub][1][t];
      v = v * s7 + (double)acc[sub][0][t];
      v = v * s7;
      const unsigned long long bal = __ballot(v >= 1.0);
      const int mrow = bM + waveM * 64 + sub * 32 + (t & 3) + 8 * (t >> 2);
      if (lane == 0) {
        s1b[(size_t)mrow * kFeatWords + word] = (unsigned)bal;
        s1T[(size_t)word * kB + mrow] = (unsigned)bal;
      }
      if (lane == 32) {
        s1b[(size_t)(mrow + 4) * kFeatWords + word] = (unsigned)(bal >> 32);
        s1T[(size_t)word * kB + mrow + 4] = (unsigned)(bal >> 32);
      }
      if (fabs(v - 1.0) <= kTau1) {
        const unsigned idx = atomicAdd(cnt, 1u);
        if (idx < kCap1) list[idx] = ((unsigned)(mrow + 4 * half) << 13) | (unsigned)fcol;
      }
    }
  }
}

// exact fp64 recompute of flagged FC1 dots; fixes s1b AND s1T
__global__ __launch_bounds__(256) void fc1_correct(
    const float* __restrict__ x, const float* __restrict__ W1,
    const unsigned* __restrict__ cnt, const unsigned* __restrict__ list,
    unsigned* __restrict__ s1b, unsigned* __restrict__ s1T) {
  const unsigned n = min(cnt[0], kCap1);
  const int lane = threadIdx.x & 63;
  const int wid = (blockIdx.x * 256 + threadIdx.x) >> 6;
  const int nw = (gridDim.x * 256) >> 6;
  for (unsigned i = wid; i < n; i += nw) {
    const unsigned u = list[i];
    const int b = (int)(u >> 13);
    const int f = (int)(u & 8191u);
    double s = 0.0;
    for (int k = lane; k < kIn; k += 64)
      s = fma((double)x[(size_t)b * kIn + k], (double)W1[(size_t)f * kIn + k], s);
#pragma unroll
    for (int off = 32; off > 0; off >>= 1) s += __shfl_down(s, off);
    if (lane == 0) {
      const unsigned mask = 1u << (f & 31);
      unsigned* p1 = s1b + (size_t)b * kFeatWords + (f >> 5);
      unsigned* p2 = s1T + (size_t)(f >> 5) * kB + b;
      if (s >= 1.0) { atomicOr(p1, mask); atomicOr(p2, mask); }
      else          { atomicAnd(p1, ~mask); atomicAnd(p2, ~mask); }
    }
  }
}

// ---------------------------------------------------------------------------
// FC2 v7: barrier-free register-dbuf, 2-wave blocks (tile 32 rows x 64 outs),
// grid (128, 8) = 1024 blocks -> 8 blocks/CU for latency interleave. A bits
// from s1T, B frags dwordx4 from L2. XCD swizzle: each XCD owns one N-panel.
// ---------------------------------------------------------------------------
__global__ __launch_bounds__(128, 4) void fc2_v7(
    const unsigned* __restrict__ s1T, const signed char* __restrict__ w2lF,
    float* __restrict__ out, unsigned* __restrict__ cnt,
    unsigned* __restrict__ list) {
  const int tid = threadIdx.x;
  const int lane = tid & 63;
  const int ln31 = lane & 31;
  const int half = lane >> 5;
  const int wvN = tid >> 6;    // 0..1 (waveN)

  const int lin = blockIdx.x + 128 * blockIdx.y;    // 0..1023
  const int sw = ((lin & 7) << 7) + (lin >> 3);     // 1024 = 8*128
  const int bx = sw >> 7;      // N-block (64 outs), 0..7
  const int bM = (sw & 127) * 32;

  const unsigned* const aptr = s1T + bM + ln31;
  const int fl = wvN * 32 + ln31;
  const signed char* const bbase =
      w2lF + (size_t)(bx * 98) * 12288 + half * 1024u + fl * 16u;

  v16i acc[3] = {};
  v4i b0[6], b1[6];
  uint2 a0, a1;

#define LOAD_TILE(nk, bf, ab)                                   \
  {                                                             \
    const signed char* bp = bbase + (size_t)(nk) * 12288;       \
    bf[0] = *(const v4i*)(bp);                                  \
    bf[1] = *(const v4i*)(bp + 2048);                           \
    bf[2] = *(const v4i*)(bp + 4096);                           \
    bf[3] = *(const v4i*)(bp + 6144);                           \
    bf[4] = *(const v4i*)(bp + 8192);                           \
    bf[5] = *(const v4i*)(bp + 10240);                          \
    (ab).x = aptr[(size_t)((nk) * 2) * kB];                     \
    (ab).y = aptr[(size_t)((nk) * 2 + 1) * kB];                 \
  }
#define COMPUTE_TILE(bf, ab)                                                    \
  {                                                                             \
    _Pragma("unroll")                                                           \
    for (int kk = 0; kk < 2; ++kk) {                                            \
      const unsigned word = kk ? (ab).y : (ab).x;                               \
      const v4i a = expand16((word >> (half * 16)) & 0xFFFFu);                  \
      acc[0] = __builtin_amdgcn_mfma_i32_32x32x32_i8(a, bf[kk], acc[0], 0,0,0); \
      acc[1] = __builtin_amdgcn_mfma_i32_32x32x32_i8(a, bf[2+kk], acc[1],0,0,0);\
      acc[2] = __builtin_amdgcn_mfma_i32_32x32x32_i8(a, bf[4+kk], acc[2],0,0,0);\
    }                                                                           \
  }

  LOAD_TILE(0, b0, a0);
  for (int kt = 0; kt + 2 <= 98; kt += 2) {
    LOAD_TILE(kt + 1, b1, a1);
    COMPUTE_TILE(b0, a0);
    const int nk2 = (kt + 2 < 98) ? kt + 2 : 97;  // last reload harmless
    LOAD_TILE(nk2, b0, a0);
    COMPUTE_TILE(b1, a1);
  }

  const double s7 = 0.0078125;
  const int o = bx * 64 + wvN * 32 + ln31;
#pragma unroll
  for (int t = 0; t < 16; ++t) {
    double v = (double)acc[2][t];
    v = v * s7 + (double)acc[1][t];
    v = v * s7 + (double)acc[0][t];
    v = v * s7;
    const int b = bM + (t & 3) + 8 * (t >> 2) + 4 * half;
    if (o < kOut) {
      out[(size_t)b * kOut + o] = (v >= 1.0) ? 1.0f : 0.0f;
      if (fabs(v - 1.0) <= kTau2) {
        const unsigned idx = atomicAdd(cnt, 1u);
        if (idx < kCap2) list[idx] = ((unsigned)b << 13) | (unsigned)o;
      }
    }
  }
#undef LOAD_TILE
#undef COMPUTE_TILE
}

// exact fp64 recompute of flagged FC2 dots (reads row-major s1b)
__global__ __launch_bounds__(256) void fc2_correct(
    const unsigned* __restrict__ s1b, const float* __restrict__ W2,
    const unsigned* __restrict__ cnt, const unsigned* __restrict__ list,
    float* __restrict__ out) {
  const unsigned n = min(cnt[0], kCap2);
  const int lane = threadIdx.x & 63;
  const int wid = (blockIdx.x * 256 + threadIdx.x) >> 6;
  const int nw = (gridDim.x * 256) >> 6;
  for (unsigned i = wid; i < n; i += nw) {
    const unsigned u = list[i];
    const int b = (int)(u >> 13);
    const int o = (int)(u & 8191u);
    double s = 0.0;
    for (int k = lane; k < kFeat; k += 64) {
      const unsigned w = s1b[(size_t)b * kFeatWords + (k >> 5)];
      if ((w >> (k & 31)) & 1u) s += (double)W2[(size_t)o * kFeat + k];
    }
#pragma unroll
    for (int off = 32; off > 0; off >>= 1) s += __shfl_down(s, off);
    if (lane == 0) out[(size_t)b * kOut + o] = (s >= 1.0) ? 1.0f : 0.0f;
  }
}

// ---------------------------------------------------------------------------
// fp64 fallback (round-1 validated) — only if ws too small.
// ---------------------------------------------------------------------------
__global__ __launch_bounds__(256) void snn_fc1(const float* __restrict__ x,
                                               const float* __restrict__ W1,
                                               unsigned int* __restrict__ s1bits) {
  __shared__ double Xd[32][66];
  __shared__ double Wd[32][66];
  __shared__ unsigned int spikes[64][2];
  const int tid = threadIdx.x;
  const int tx = tid & 15;
  const int ty = tid >> 4;
  const int b0 = blockIdx.y * 64;
  const int f0 = blockIdx.x * 64;
  if (tid < 128) spikes[tid >> 1][tid & 1] = 0u;
  double acc[4][4];
#pragma unroll
  for (int j = 0; j < 4; ++j)
#pragma unroll
    for (int i = 0; i < 4; ++i) acc[j][i] = 0.0;
  const int rl = tid >> 2;
  const int kq = (tid & 3) * 8;
  const float* xrow = x + (size_t)(b0 + rl) * kIn + kq;
  const float* wrow = W1 + (size_t)(f0 + rl) * kIn + kq;
  for (int kc = 0; kc < kIn; kc += 32) {
    const float4 xv0 = *(const float4*)(xrow + kc);
    const float4 xv1 = *(const float4*)(xrow + kc + 4);
    const float4 wv0 = *(const float4*)(wrow + kc);
    const float4 wv1 = *(const float4*)(wrow + kc + 4);
    __syncthreads();
    Xd[kq + 0][rl] = (double)xv0.x; Xd[kq + 1][rl] = (double)xv0.y;
    Xd[kq + 2][rl] = (double)xv0.z; Xd[kq + 3][rl] = (double)xv0.w;
    Xd[kq + 4][rl] = (double)xv1.x; Xd[kq + 5][rl] = (double)xv1.y;
    Xd[kq + 6][rl] = (double)xv1.z; Xd[kq + 7][rl] = (double)xv1.w;
    Wd[kq + 0][rl] = (double)wv0.x; Wd[kq + 1][rl] = (double)wv0.y;
    Wd[kq + 2][rl] = (double)wv0.z; Wd[kq + 3][rl] = (double)wv0.w;
    Wd[kq + 4][rl] = (double)wv1.x; Wd[kq + 5][rl] = (double)wv1.y;
    Wd[kq + 6][rl] = (double)wv1.z; Wd[kq + 7][rl] = (double)wv1.w;
    __syncthreads();
#pragma unroll
    for (int k = 0; k < 32; ++k) {
      const double2 xa = *(const double2*)&Xd[k][ty * 4];
      const double2 xb = *(const double2*)&Xd[k][ty * 4 + 2];
      const double2 wa = *(const double2*)&Wd[k][tx * 4];
      const double2 wb = *(const double2*)&Wd[k][tx * 4 + 2];
      const double xv[4] = {xa.x, xa.y, xb.x, xb.y};
      const double wv[4] = {wa.x, wa.y, wb.x, wb.y};
#pragma unroll
      for (int j = 0; j < 4; ++j)
#pragma unroll
        for (int i = 0; i < 4; ++i) acc[j][i] += xv[j] * wv[i];
    }
  }
  __syncthreads();
#pragma unroll
  for (int j = 0; j < 4; ++j) {
    unsigned int nib = 0u;
#pragma unroll
    for (int i = 0; i < 4; ++i) nib |= (acc[j][i] >= 1.0 ? 1u : 0u) << i;
    atomicOr(&spikes[ty * 4 + j][tx >> 3], nib << ((tx * 4) & 31));
  }
  __syncthreads();
  if (tid < 128) {
    const int r = tid >> 1;
    const int w = tid & 1;
    s1bits[(size_t)(b0 + r) * kFeatWords + (f0 >> 5) + w] = spikes[r][w];
  }
}

__global__ __launch_bounds__(256) void snn_fc2(const unsigned int* __restrict__ s1bits,
                                               const float* __restrict__ W2,
                                               float* __restrict__ out) {
  __shared__ double Wd[32][66];
  __shared__ unsigned int Sb[64];
  const int tid = threadIdx.x;
  const int tx = tid & 15;
  const int ty = tid >> 4;
  const int b0 = blockIdx.y * 64;
  const int o0 = blockIdx.x * 64;
  double acc[4][4];
#pragma unroll
  for (int j = 0; j < 4; ++j)
#pragma unroll
    for (int i = 0; i < 4; ++i) acc[j][i] = 0.0;
  const int rl = tid >> 2;
  const int kq = (tid & 3) * 8;
  int orow = o0 + rl;
  if (orow >= kOut) orow = kOut - 1;
  const float* wrow = W2 + (size_t)orow * kFeat + kq;
  for (int kc = 0; kc < kFeat; kc += 32) {
    const float4 wv0 = *(const float4*)(wrow + kc);
    const float4 wv1 = *(const float4*)(wrow + kc + 4);
    unsigned int sword = 0u;
    if (tid < 64) sword = s1bits[(size_t)(b0 + tid) * kFeatWords + (kc >> 5)];
    __syncthreads();
    Wd[kq + 0][rl] = (double)wv0.x; Wd[kq + 1][rl] = (double)wv0.y;
    Wd[kq + 2][rl] = (double)wv0.z; Wd[kq + 3][rl] = (double)wv0.w;
    Wd[kq + 4][rl] = (double)wv1.x; Wd[kq + 5][rl] = (double)wv1.y;
    Wd[kq + 6][rl] = (double)wv1.z; Wd[kq + 7][rl] = (double)wv1.w;
    if (tid < 64) Sb[tid] = sword;
    __syncthreads();
    const unsigned int rw0 = Sb[ty * 4 + 0];
    const unsigned int rw1 = Sb[ty * 4 + 1];
    const unsigned int rw2 = Sb[ty * 4 + 2];
    const unsigned int rw3 = Sb[ty * 4 + 3];
#pragma unroll
    for (int k = 0; k < 32; ++k) {
      const double2 wa = *(const double2*)&Wd[k][tx * 4];
      const double2 wb = *(const double2*)&Wd[k][tx * 4 + 2];
      const double wv[4] = {wa.x, wa.y, wb.x, wb.y};
      const double sv[4] = {(double)((rw0 >> k) & 1u), (double)((rw1 >> k) & 1u),
                            (double)((rw2 >> k) & 1u), (double)((rw3 >> k) & 1u)};
#pragma unroll
      for (int j = 0; j < 4; ++j)
#pragma unroll
        for (int i = 0; i < 4; ++i) acc[j][i] += sv[j] * wv[i];
    }
  }
#pragma unroll
  for (int j = 0; j < 4; ++j) {
    const int b = b0 + ty * 4 + j;
#pragma unroll
    for (int i = 0; i < 4; ++i) {
      const int o = o0 + tx * 4 + i;
      if (o < kOut) out[(size_t)b * kOut + o] = (acc[j][i] >= 1.0) ? 1.0f : 0.0f;
    }
  }
}

extern "C" void kernel_launch(void* const* d_in, const int* in_sizes, int n_in,
                              void* d_out, int out_size, void* d_ws, size_t ws_size,
                              hipStream_t stream) {
  const float* x = (const float*)d_in[0];
  const float* W1 = (const float*)d_in[1];
  const float* W2 = (const float*)d_in[2];
  float* out = (float*)d_out;

  char* p = (char*)d_ws;
  signed char* w1lF = (signed char*)p;   p += kW1F;
  signed char* w2lF = (signed char*)p;   p += kW2F;
  unsigned* s1b = (unsigned*)p;          p += kS1Bytes;
  unsigned* s1T = (unsigned*)p;          p += kS1Bytes;
  signed char* xb8 = (signed char*)p;    p += kX8Bytes;
  unsigned* list1 = (unsigned*)p;        p += (size_t)kCap1 * 4;
  unsigned* list2 = (unsigned*)p;        p += (size_t)kCap2 * 4;
  unsigned* ctrs = (unsigned*)p;         p += 256;
  const size_t need = (size_t)(p - (char*)d_ws);  // ~93 MB

  if (ws_size >= need) {
    hipMemsetAsync(ctrs, 0, 32, stream);  // ctrs[0]=fc1 cnt, ctrs[4]=fc2 cnt
    conv_w1F<<<4802, 256, 0, stream>>>(W1, w1lF);
    conv_w2F<<<784, 256, 0, stream>>>(W2, w2lF);
    pack_x8<<<3136, 256, 0, stream>>>(x, xb8);
    fc1_v11<<<dim3(16, 98), 512, 0, stream>>>(xb8, w1lF, s1b, s1T, ctrs, list1);
    fc1_correct<<<1024, 256, 0, stream>>>(x, W1, ctrs, list1, s1b, s1T);
    fc2_v7<<<dim3(128, 8), 128, 0, stream>>>(s1T, w2lF, out, ctrs + 4, list2);
    fc2_correct<<<64, 256, 0, stream>>>(s1b, W2, ctrs + 4, list2, out);
  } else {
    unsigned* s1 = (unsigned*)d_ws;
    snn_fc1<<<dim3(98, 64), 256, 0, stream>>>(x, W1, s1);
    snn_fc2<<<dim3(8, 64), 256, 0, stream>>>(s1, W2, out);
  }
}

// Round 8
// 662.380 us; speedup vs baseline: 1.0283x; 1.0283x over previous
//
#include <hip/hip_runtime.h>

// SNN 2-layer forward: s2 = (( (x@W1.T >=1) @ W2.T) >= 1)
// B=4096, IN=3136, FEAT=6272, OUT=500; x and s1 binary {0,1}.
// Exact 3-limb i8-MFMA GEMM + worst-case-safe sparse fp64 correction.
//
// Round-16: v11 (pre-expanded A in global) regressed 258->410us: VALUBusy
// 42->10 (expansion gone) but A-loads became L3/HBM-latency events inside
// the per-kt drain (FETCH 354MB). Bit-A from xb2 (1.6MB, cache-resident)
// is load-bearing -> reverted. The untried lever is the catalog's proven
// quadrant: dual-barrier-per-phase template (m201/m218) — {ds_read subtile;
// stage; barrier; lgkmcnt(0); setprio(1); MFMA cluster; setprio(0);
// barrier} x2 phases/kt, 3-buffer LDS, stages 2kt ahead, vmcnt counted
// once per kt (2/1, never 0), expand16 pre-barrier (off critical path),
// sched_barrier(0) after lgkm (rule #18). T5 setprio pays only in this
// structure (m218b). v10 tiling kept: wave 64x32, 12 MFMA/kt, acc 96 AGPR.

namespace {
constexpr int kB = 4096;
constexpr int kIn = 3136;        // 49 chunks of 64
constexpr int kFeat = 6272;      // 98 chunks of 64
constexpr int kFeatWords = 196;  // u32 per s1 row
constexpr int kOut = 500;
constexpr size_t kPlane1 = (size_t)kFeat * kIn;
constexpr size_t kW1F = 3 * kPlane1;                 // 59,006,976 (4802*12288)
constexpr size_t kW2F = (size_t)784 * 12288;         // 9,633,792
constexpr size_t kS1Bytes = (size_t)kB * kFeatWords * 4;  // 3,211,264 (x2)
constexpr size_t kXb2Bytes = (size_t)49 * kB * 8;    // 1,605,632
constexpr unsigned kCap1 = 1u << 20;
constexpr unsigned kCap2 = 1u << 16;
__device__ constexpr double kTau1 = 7.4769e-4;       // > 3136*2^-22
__device__ constexpr double kTau2 = 1.4955e-3;       // > 6272*2^-22
}  // namespace

typedef int v4i __attribute__((ext_vector_type(4)));
typedef int v16i __attribute__((ext_vector_type(16)));

__device__ __forceinline__ void gload_lds16(const void* g, void* l) {
  __builtin_amdgcn_global_load_lds((__attribute__((address_space(1))) void*)(g),
                                   (__attribute__((address_space(3))) void*)(l),
                                   16, 0, 0);
}

// 16 bits -> 16 i8 (byte i = bit i)
__device__ __forceinline__ v4i expand16(unsigned b) {
  unsigned u0 = (((b      ) & 0xFu) * 0x204081u) & 0x01010101u;
  unsigned u1 = (((b >> 4 ) & 0xFu) * 0x204081u) & 0x01010101u;
  unsigned u2 = (((b >> 8 ) & 0xFu) * 0x204081u) & 0x01010101u;
  unsigned u3 = (((b >> 12) & 0xFu) * 0x204081u) & 0x01010101u;
  return (v4i){(int)u0, (int)u1, (int)u2, (int)u3};
}

// exact 3-digit signed base-128 split; |w - sum| <= 2^-22
__device__ __forceinline__ void split3(float w, signed char* d) {
  float c = rintf(w * 128.f);
  d[0] = (signed char)(int)c;
  float r = fmaf(c, -7.8125e-03f, w);
  c = rintf(r * 16384.f);
  d[1] = (signed char)(int)c;
  r = fmaf(c, -6.103515625e-05f, r);
  c = rintf(r * 2097152.f);
  d[2] = (signed char)(int)c;
}

// ---------------------------------------------------------------------------
// W1 -> fragment-major limbs: slot(fb,kt,j,g) = 1KB of 64 feats x 16 k-bytes.
// ---------------------------------------------------------------------------
__global__ __launch_bounds__(256) void conv_w1F(const float* __restrict__ W,
                                                signed char* __restrict__ F) {
  const int bx = blockIdx.x;               // fb*49 + kt, < 4802
  const int fb = bx / 49;
  const int kt = bx % 49;
  const int f = threadIdx.x & 63;
  const int g = threadIdx.x >> 6;
  const float* src = W + (size_t)(fb * 64 + f) * kIn + kt * 64 + g * 16;
  union { signed char c[16]; int4 v; } o[3];
#pragma unroll
  for (int q = 0; q < 4; ++q) {
    const float4 w = *(const float4*)(src + q * 4);
    signed char d[4][3];
    split3(w.x, d[0]); split3(w.y, d[1]); split3(w.z, d[2]); split3(w.w, d[3]);
#pragma unroll
    for (int e = 0; e < 4; ++e)
#pragma unroll
      for (int j = 0; j < 3; ++j) o[j].c[q * 4 + e] = d[e][j];
  }
#pragma unroll
  for (int j = 0; j < 3; ++j)
    *(int4*)(F + ((size_t)bx * 3 + j) * 4096 + g * 1024 + f * 16) = o[j].v;
}

// W2 (padded to 512 rows) -> fragment-major limbs, slots (fb<8, kt<98, j, g)
__global__ __launch_bounds__(256) void conv_w2F(const float* __restrict__ W,
                                                signed char* __restrict__ F) {
  const int bx = blockIdx.x;               // fb*98 + kt, < 784
  const int fb = bx / 98;
  const int kt = bx % 98;
  const int f = threadIdx.x & 63;
  const int g = threadIdx.x >> 6;
  const int feat = fb * 64 + f;
  union { signed char c[16]; int4 v; } o[3];
#pragma unroll
  for (int q = 0; q < 4; ++q) {
    float4 w = {0.f, 0.f, 0.f, 0.f};
    if (feat < kOut)
      w = *(const float4*)(W + (size_t)feat * kFeat + kt * 64 + g * 16 + q * 4);
    signed char d[4][3];
    split3(w.x, d[0]); split3(w.y, d[1]); split3(w.z, d[2]); split3(w.w, d[3]);
#pragma unroll
    for (int e = 0; e < 4; ++e)
#pragma unroll
      for (int j = 0; j < 3; ++j) o[j].c[q * 4 + e] = d[e][j];
  }
#pragma unroll
  for (int j = 0; j < 3; ++j)
    *(int4*)(F + ((size_t)bx * 3 + j) * 4096 + g * 1024 + f * 16) = o[j].v;
}

// x -> transposed packed bits: xb2[kt*4096 + b]
__global__ __launch_bounds__(256) void pack_x2(const float* __restrict__ X,
                                               uint2* __restrict__ xb2) {
  const int wid = (blockIdx.x * 256 + threadIdx.x) >> 6;  // < 200,704
  const int lane = threadIdx.x & 63;
  const int b = wid / 49;
  const int g = wid % 49;
  const float v = X[(size_t)b * kIn + g * 64 + lane];
  const unsigned long long bal = __ballot(v != 0.f);
  if (lane == 0) xb2[(size_t)g * kB + b] = make_uint2((unsigned)bal, (unsigned)(bal >> 32));
}

// ---------------------------------------------------------------------------
// FC1 v12: tile M=256,N=64,BK=64; 512 thr = 8 waves (4 waveM x 2 waveN),
// wave tile 64x32, acc[2][3] (96 AGPR). m201-template schedule: 2 phases/kt
// (one per kk), each {3 ds_read_b128; stage/A issue; barrier; lgkmcnt(0)+
// sched_barrier; setprio(1); 6 MFMA; setprio(0); barrier}. 3x12KB LDS
// buffers, stages 2 kt ahead, per-kt counted vmcnt(2)/(1) (never 0 until
// tail). expand16 runs pre-barrier (off the post-lgkm critical path).
// vmcnt ledger (wv<4), issue order per kt: A0,A1 (ph0), g0 (ph0), g1 (ph1).
// After each kt's wait vmcnt(2): <=2 outstanding (this kt's g0,g1);
// certifies prev-kt stages (buf kt+1) + this kt's A (= A of kt+1). wv>=4:
// A0,A1,g0 -> vmcnt(1). Grid (16,98); XCD swizzle 1568=8*196.
// ---------------------------------------------------------------------------
__global__ __launch_bounds__(512, 2) void fc1_v12(
    const uint2* __restrict__ xb2, const signed char* __restrict__ w1lF,
    unsigned* __restrict__ s1b, unsigned* __restrict__ s1T,
    unsigned* __restrict__ cnt, unsigned* __restrict__ list) {
  __shared__ __align__(16) signed char lds[36864];  // 3 x 12 KB
  const int tid = threadIdx.x;
  const int lane = tid & 63;
  const int ln31 = lane & 31;
  const int half = lane >> 5;
  const int wv = tid >> 6;       // 0..7
  const int waveM = wv >> 1;     // 0..3 (64 rows each)
  const int waveN = wv & 1;      // 0..1

  // XCD swizzle: 1568 = 8*196 (bijective).
  const int lin = blockIdx.x + 16 * blockIdx.y;     // 0..1567
  const int sw = (lin & 7) * 196 + (lin >> 3);
  const int bx = sw >> 4;        // N-block (64 feats), 0..97
  const int bM = (sw & 15) * 256;

  // B staging: 12 slots/tile; wave wv stages slot wv (ph0), wv+8 (ph1, wv<4)
  const signed char* const gbase = w1lF + (size_t)bx * 49 * 12288;
  const bool has1 = (wv < 4);
  const unsigned sG0 = wv * 1024u + lane * 16u;
  const unsigned sL0 = wv * 1024u;
  const unsigned sG1 = (wv + 8) * 1024u + lane * 16u;
  const unsigned sL1 = (wv + 8) * 1024u;

  const uint2* const aptr = xb2 + bM + waveM * 64 + ln31;  // sub0; sub1=+32
  const unsigned bfeat = (waveN * 32 + ln31) * 16u;

  v16i acc[2][3] = {};
  uint2 aC0, aC1, aN0, aN1;
  v4i a00, a10, a01, a11;  // expanded A frags (sub, kk)

  // ---- prologue: A(0); S(0)->buf0; S(1)->buf1; certify A(0)+S(0) ----
  aC0 = aptr[0];
  aC1 = aptr[32];
  gload_lds16(gbase + sG0, lds + sL0);
  if (has1) gload_lds16(gbase + sG1, lds + sL1);
  gload_lds16(gbase + 12288 + sG0, lds + 12288 + sL0);
  if (has1) gload_lds16(gbase + 12288 + sG1, lds + 12288 + sL1);
  if (has1) asm volatile("s_waitcnt vmcnt(2)" ::: "memory");
  else      asm volatile("s_waitcnt vmcnt(1)" ::: "memory");
  __builtin_amdgcn_s_barrier();
  asm volatile("" ::: "memory");

  const uint2* apn = aptr + (size_t)kB;          // -> A(1)
  const signed char* gst = gbase + 2 * 12288;    // -> S(2)

  // one 6-MFMA cluster
#define FC1_MM(AS0, AS1, B0, B1, B2)                                          \
  acc[0][0] = __builtin_amdgcn_mfma_i32_32x32x32_i8(AS0, B0, acc[0][0],0,0,0);\
  acc[0][1] = __builtin_amdgcn_mfma_i32_32x32x32_i8(AS0, B1, acc[0][1],0,0,0);\
  acc[0][2] = __builtin_amdgcn_mfma_i32_32x32x32_i8(AS0, B2, acc[0][2],0,0,0);\
  acc[1][0] = __builtin_amdgcn_mfma_i32_32x32x32_i8(AS1, B0, acc[1][0],0,0,0);\
  acc[1][1] = __builtin_amdgcn_mfma_i32_32x32x32_i8(AS1, B1, acc[1][1],0,0,0);\
  acc[1][2] = __builtin_amdgcn_mfma_i32_32x32x32_i8(AS1, B2, acc[1][2],0,0,0)

  // phase 0 of kt: kk=0. Expands ALL of this kt's A frags (pre-barrier),
  // issues A(kt+1) + stage slot g0 -> SB.
#define FC1_PH0(CB, SB, DO_A, DO_S)                                           \
  {                                                                           \
    a00 = expand16((aC0.x >> (half * 16)) & 0xFFFFu);                         \
    a10 = expand16((aC1.x >> (half * 16)) & 0xFFFFu);                         \
    a01 = expand16((aC0.y >> (half * 16)) & 0xFFFFu);                         \
    a11 = expand16((aC1.y >> (half * 16)) & 0xFFFFu);                         \
    const v4i b0 = *(const v4i*)(lds + (CB) + 0 * 4096 + half * 1024u + bfeat);\
    const v4i b1 = *(const v4i*)(lds + (CB) + 1 * 4096 + half * 1024u + bfeat);\
    const v4i b2 = *(const v4i*)(lds + (CB) + 2 * 4096 + half * 1024u + bfeat);\
    if (DO_A) { aN0 = apn[0]; aN1 = apn[32]; apn += (size_t)kB; }             \
    if (DO_S) { gload_lds16(gst + sG0, lds + (SB) + sL0); }                   \
    asm volatile("" ::: "memory");                                            \
    __builtin_amdgcn_s_barrier();                                             \
    asm volatile("s_waitcnt lgkmcnt(0)" ::: "memory");                        \
    __builtin_amdgcn_sched_barrier(0);                                        \
    __builtin_amdgcn_s_setprio(1);                                            \
    FC1_MM(a00, a10, b0, b1, b2);                                             \
    __builtin_amdgcn_s_setprio(0);                                            \
    __builtin_amdgcn_s_barrier();                                             \
    asm volatile("" ::: "memory");                                            \
  }

  // phase 1 of kt: kk=1. Issues stage slot g1 (wv<4); counted vmcnt; WAITM:
  // 2 = steady vmcnt(2)/(1); 0 = vmcnt(0) (kt=47); -1 = none (kt=48).
#define FC1_PH1(CB, SB, DO_S, WAITM)                                          \
  {                                                                           \
    const v4i b0 = *(const v4i*)(lds + (CB) + 0 * 4096 + (2 + half) * 1024u + bfeat);\
    const v4i b1 = *(const v4i*)(lds + (CB) + 1 * 4096 + (2 + half) * 1024u + bfeat);\
    const v4i b2 = *(const v4i*)(lds + (CB) + 2 * 4096 + (2 + half) * 1024u + bfeat);\
    if ((DO_S) && has1) { gload_lds16(gst + sG1, lds + (SB) + sL1); }         \
    if ((DO_S)) gst += 12288;                                                 \
    if ((WAITM) == 2) {                                                       \
      if (has1) asm volatile("s_waitcnt vmcnt(2)" ::: "memory");              \
      else      asm volatile("s_waitcnt vmcnt(1)" ::: "memory");              \
    } else if ((WAITM) == 0) {                                                \
      asm volatile("s_waitcnt vmcnt(0)" ::: "memory");                        \
    }                                                                         \
    asm volatile("" ::: "memory");                                            \
    __builtin_amdgcn_s_barrier();                                             \
    asm volatile("s_waitcnt lgkmcnt(0)" ::: "memory");                        \
    __builtin_amdgcn_sched_barrier(0);                                        \
    __builtin_amdgcn_s_setprio(1);                                            \
    FC1_MM(a01, a11, b0, b1, b2);                                             \
    __builtin_amdgcn_s_setprio(0);                                            \
    __builtin_amdgcn_s_barrier();                                             \
    asm volatile("" ::: "memory");                                            \
    aC0 = aN0; aC1 = aN1;                                                     \
  }

  // ---- main loop: kt = 0..44 (15 x 3; buffers rotate 0,1,2) ----
  for (int t = 0; t < 15; ++t) {
    FC1_PH0(0,     24576, 1, 1); FC1_PH1(0,     24576, 1, 2);
    FC1_PH0(12288, 0,     1, 1); FC1_PH1(12288, 0,     1, 2);
    FC1_PH0(24576, 12288, 1, 1); FC1_PH1(24576, 12288, 1, 2);
  }
  // ---- peeled tail ----
  FC1_PH0(0,     24576, 1, 1); FC1_PH1(0,     24576, 1, 2);  // kt=45: A46,S47
  FC1_PH0(12288, 0,     1, 1); FC1_PH1(12288, 0,     1, 2);  // kt=46: A47,S48
  FC1_PH0(24576, 0,     1, 0); FC1_PH1(24576, 0,     0, 0);  // kt=47: A48; drain
  FC1_PH0(0,     0,     0, 0); FC1_PH1(0,     0,     0, -1); // kt=48
#undef FC1_PH0
#undef FC1_PH1
#undef FC1_MM

  const double s7 = 0.0078125;
  const int word = bx * 2 + waveN;
  const int fcol = word * 32 + ln31;
#pragma unroll
  for (int sub = 0; sub < 2; ++sub) {
#pragma unroll
    for (int t = 0; t < 16; ++t) {
      double v = (double)acc[sub][2][t];
      v = v * s7 + (double)acc[sub][1][t];
      v = v * s7 + (double)acc[sub][0][t];
      v = v * s7;
      const unsigned long long bal = __ballot(v >= 1.0);
      const int mrow = bM + waveM * 64 + sub * 32 + (t & 3) + 8 * (t >> 2);
      if (lane == 0) {
        s1b[(size_t)mrow * kFeatWords + word] = (unsigned)bal;
        s1T[(size_t)word * kB + mrow] = (unsigned)bal;
      }
      if (lane == 32) {
        s1b[(size_t)(mrow + 4) * kFeatWords + word] = (unsigned)(bal >> 32);
        s1T[(size_t)word * kB + mrow + 4] = (unsigned)(bal >> 32);
      }
      if (fabs(v - 1.0) <= kTau1) {
        const unsigned idx = atomicAdd(cnt, 1u);
        if (idx < kCap1) list[idx] = ((unsigned)(mrow + 4 * half) << 13) | (unsigned)fcol;
      }
    }
  }
}

// exact fp64 recompute of flagged FC1 dots; fixes s1b AND s1T
__global__ __launch_bounds__(256) void fc1_correct(
    const float* __restrict__ x, const float* __restrict__ W1,
    const unsigned* __restrict__ cnt, const unsigned* __restrict__ list,
    unsigned* __restrict__ s1b, unsigned* __restrict__ s1T) {
  const unsigned n = min(cnt[0], kCap1);
  const int lane = threadIdx.x & 63;
  const int wid = (blockIdx.x * 256 + threadIdx.x) >> 6;
  const int nw = (gridDim.x * 256) >> 6;
  for (unsigned i = wid; i < n; i += nw) {
    const unsigned u = list[i];
    const int b = (int)(u >> 13);
    const int f = (int)(u & 8191u);
    double s = 0.0;
    for (int k = lane; k < kIn; k += 64)
      s = fma((double)x[(size_t)b * kIn + k], (double)W1[(size_t)f * kIn + k], s);
#pragma unroll
    for (int off = 32; off > 0; off >>= 1) s += __shfl_down(s, off);
    if (lane == 0) {
      const unsigned mask = 1u << (f & 31);
      unsigned* p1 = s1b + (size_t)b * kFeatWords + (f >> 5);
      unsigned* p2 = s1T + (size_t)(f >> 5) * kB + b;
      if (s >= 1.0) { atomicOr(p1, mask); atomicOr(p2, mask); }
      else          { atomicAnd(p1, ~mask); atomicAnd(p2, ~mask); }
    }
  }
}

// ---------------------------------------------------------------------------
// FC2 v7: barrier-free register-dbuf, 2-wave blocks (tile 32 rows x 64 outs),
// grid (128, 8) = 1024 blocks -> 8 blocks/CU for latency interleave. A bits
// from s1T, B frags dwordx4 from L2. XCD swizzle: each XCD owns one N-panel.
// ---------------------------------------------------------------------------
__global__ __launch_bounds__(128, 4) void fc2_v7(
    const unsigned* __restrict__ s1T, const signed char* __restrict__ w2lF,
    float* __restrict__ out, unsigned* __restrict__ cnt,
    unsigned* __restrict__ list) {
  const int tid = threadIdx.x;
  const int lane = tid & 63;
  const int ln31 = lane & 31;
  const int half = lane >> 5;
  const int wvN = tid >> 6;    // 0..1 (waveN)

  const int lin = blockIdx.x + 128 * blockIdx.y;    // 0..1023
  const int sw = ((lin & 7) << 7) + (lin >> 3);     // 1024 = 8*128
  const int bx = sw >> 7;      // N-block (64 outs), 0..7
  const int bM = (sw & 127) * 32;

  const unsigned* const aptr = s1T + bM + ln31;
  const int fl = wvN * 32 + ln31;
  const signed char* const bbase =
      w2lF + (size_t)(bx * 98) * 12288 + half * 1024u + fl * 16u;

  v16i acc[3] = {};
  v4i b0[6], b1[6];
  uint2 a0, a1;

#define LOAD_TILE(nk, bf, ab)                                   \
  {                                                             \
    const signed char* bp = bbase + (size_t)(nk) * 12288;       \
    bf[0] = *(const v4i*)(bp);                                  \
    bf[1] = *(const v4i*)(bp + 2048);                           \
    bf[2] = *(const v4i*)(bp + 4096);                           \
    bf[3] = *(const v4i*)(bp + 6144);                           \
    bf[4] = *(const v4i*)(bp + 8192);                           \
    bf[5] = *(const v4i*)(bp + 10240);                          \
    (ab).x = aptr[(size_t)((nk) * 2) * kB];                     \
    (ab).y = aptr[(size_t)((nk) * 2 + 1) * kB];                 \
  }
#define COMPUTE_TILE(bf, ab)                                                    \
  {                                                                             \
    _Pragma("unroll")                                                           \
    for (int kk = 0; kk < 2; ++kk) {                                            \
      const unsigned word = kk ? (ab).y : (ab).x;                               \
      const v4i a = expand16((word >> (half * 16)) & 0xFFFFu);                  \
      acc[0] = __builtin_amdgcn_mfma_i32_32x32x32_i8(a, bf[kk], acc[0], 0,0,0); \
      acc[1] = __builtin_amdgcn_mfma_i32_32x32x32_i8(a, bf[2+kk], acc[1],0,0,0);\
      acc[2] = __builtin_amdgcn_mfma_i32_32x32x32_i8(a, bf[4+kk], acc[2],0,0,0);\
    }                                                                           \
  }

  LOAD_TILE(0, b0, a0);
  for (int kt = 0; kt + 2 <= 98; kt += 2) {
    LOAD_TILE(kt + 1, b1, a1);
    COMPUTE_TILE(b0, a0);
    const int nk2 = (kt + 2 < 98) ? kt + 2 : 97;  // last reload harmless
    LOAD_TILE(nk2, b0, a0);
    COMPUTE_TILE(b1, a1);
  }

  const double s7 = 0.0078125;
  const int o = bx * 64 + wvN * 32 + ln31;
#pragma unroll
  for (int t = 0; t < 16; ++t) {
    double v = (double)acc[2][t];
    v = v * s7 + (double)acc[1][t];
    v = v * s7 + (double)acc[0][t];
    v = v * s7;
    const int b = bM + (t & 3) + 8 * (t >> 2) + 4 * half;
    if (o < kOut) {
      out[(size_t)b * kOut + o] = (v >= 1.0) ? 1.0f : 0.0f;
      if (fabs(v - 1.0) <= kTau2) {
        const unsigned idx = atomicAdd(cnt, 1u);
        if (idx < kCap2) list[idx] = ((unsigned)b << 13) | (unsigned)o;
      }
    }
  }
#undef LOAD_TILE
#undef COMPUTE_TILE
}

// exact fp64 recompute of flagged FC2 dots (reads row-major s1b)
__global__ __launch_bounds__(256) void fc2_correct(
    const unsigned* __restrict__ s1b, const float* __restrict__ W2,
    const unsigned* __restrict__ cnt, const unsigned* __restrict__ list,
    float* __restrict__ out) {
  const unsigned n = min(cnt[0], kCap2);
  const int lane = threadIdx.x & 63;
  const int wid = (blockIdx.x * 256 + threadIdx.x) >> 6;
  const int nw = (gridDim.x * 256) >> 6;
  for (unsigned i = wid; i < n; i += nw) {
    const unsigned u = list[i];
    const int b = (int)(u >> 13);
    const int o = (int)(u & 8191u);
    double s = 0.0;
    for (int k = lane; k < kFeat; k += 64) {
      const unsigned w = s1b[(size_t)b * kFeatWords + (k >> 5)];
      if ((w >> (k & 31)) & 1u) s += (double)W2[(size_t)o * kFeat + k];
    }
#pragma unroll
    for (int off = 32; off > 0; off >>= 1) s += __shfl_down(s, off);
    if (lane == 0) out[(size_t)b * kOut + o] = (s >= 1.0) ? 1.0f : 0.0f;
  }
}

// ---------------------------------------------------------------------------
// fp64 fallback (round-1 validated) — only if ws too small.
// ---------------------------------------------------------------------------
__global__ __launch_bounds__(256) void snn_fc1(const float* __restrict__ x,
                                               const float* __restrict__ W1,
                                               unsigned int* __restrict__ s1bits) {
  __shared__ double Xd[32][66];
  __shared__ double Wd[32][66];
  __shared__ unsigned int spikes[64][2];
  const int tid = threadIdx.x;
  const int tx = tid & 15;
  const int ty = tid >> 4;
  const int b0 = blockIdx.y * 64;
  const int f0 = blockIdx.x * 64;
  if (tid < 128) spikes[tid >> 1][tid & 1] = 0u;
  double acc[4][4];
#pragma unroll
  for (int j = 0; j < 4; ++j)
#pragma unroll
    for (int i = 0; i < 4; ++i) acc[j][i] = 0.0;
  const int rl = tid >> 2;
  const int kq = (tid & 3) * 8;
  const float* xrow = x + (size_t)(b0 + rl) * kIn + kq;
  const float* wrow = W1 + (size_t)(f0 + rl) * kIn + kq;
  for (int kc = 0; kc < kIn; kc += 32) {
    const float4 xv0 = *(const float4*)(xrow + kc);
    const float4 xv1 = *(const float4*)(xrow + kc + 4);
    const float4 wv0 = *(const float4*)(wrow + kc);
    const float4 wv1 = *(const float4*)(wrow + kc + 4);
    __syncthreads();
    Xd[kq + 0][rl] = (double)xv0.x; Xd[kq + 1][rl] = (double)xv0.y;
    Xd[kq + 2][rl] = (double)xv0.z; Xd[kq + 3][rl] = (double)xv0.w;
    Xd[kq + 4][rl] = (double)xv1.x; Xd[kq + 5][rl] = (double)xv1.y;
    Xd[kq + 6][rl] = (double)xv1.z; Xd[kq + 7][rl] = (double)xv1.w;
    Wd[kq + 0][rl] = (double)wv0.x; Wd[kq + 1][rl] = (double)wv0.y;
    Wd[kq + 2][rl] = (double)wv0.z; Wd[kq + 3][rl] = (double)wv0.w;
    Wd[kq + 4][rl] = (double)wv1.x; Wd[kq + 5][rl] = (double)wv1.y;
    Wd[kq + 6][rl] = (double)wv1.z; Wd[kq + 7][rl] = (double)wv1.w;
    __syncthreads();
#pragma unroll
    for (int k = 0; k < 32; ++k) {
      const double2 xa = *(const double2*)&Xd[k][ty * 4];
      const double2 xb = *(const double2*)&Xd[k][ty * 4 + 2];
      const double2 wa = *(const double2*)&Wd[k][tx * 4];
      const double2 wb = *(const double2*)&Wd[k][tx * 4 + 2];
      const double xv[4] = {xa.x, xa.y, xb.x, xb.y};
      const double wv[4] = {wa.x, wa.y, wb.x, wb.y};
#pragma unroll
      for (int j = 0; j < 4; ++j)
#pragma unroll
        for (int i = 0; i < 4; ++i) acc[j][i] += xv[j] * wv[i];
    }
  }
  __syncthreads();
#pragma unroll
  for (int j = 0; j < 4; ++j) {
    unsigned int nib = 0u;
#pragma unroll
    for (int i = 0; i < 4; ++i) nib |= (acc[j][i] >= 1.0 ? 1u : 0u) << i;
    atomicOr(&spikes[ty * 4 + j][tx >> 3], nib << ((tx * 4) & 31));
  }
  __syncthreads();
  if (tid < 128) {
    const int r = tid >> 1;
    const int w = tid & 1;
    s1bits[(size_t)(b0 + r) * kFeatWords + (f0 >> 5) + w] = spikes[r][w];
  }
}

__global__ __launch_bounds__(256) void snn_fc2(const unsigned int* __restrict__ s1bits,
                                               const float* __restrict__ W2,
                                               float* __restrict__ out) {
  __shared__ double Wd[32][66];
  __shared__ unsigned int Sb[64];
  const int tid = threadIdx.x;
  const int tx = tid & 15;
  const int ty = tid >> 4;
  const int b0 = blockIdx.y * 64;
  const int o0 = blockIdx.x * 64;
  double acc[4][4];
#pragma unroll
  for (int j = 0; j < 4; ++j)
#pragma unroll
    for (int i = 0; i < 4; ++i) acc[j][i] = 0.0;
  const int rl = tid >> 2;
  const int kq = (tid & 3) * 8;
  int orow = o0 + rl;
  if (orow >= kOut) orow = kOut - 1;
  const float* wrow = W2 + (size_t)orow * kFeat + kq;
  for (int kc = 0; kc < kFeat; kc += 32) {
    const float4 wv0 = *(const float4*)(wrow + kc);
    const float4 wv1 = *(const float4*)(wrow + kc + 4);
    unsigned int sword = 0u;
    if (tid < 64) sword = s1bits[(size_t)(b0 + tid) * kFeatWords + (kc >> 5)];
    __syncthreads();
    Wd[kq + 0][rl] = (double)wv0.x; Wd[kq + 1][rl] = (double)wv0.y;
    Wd[kq + 2][rl] = (double)wv0.z; Wd[kq + 3][rl] = (double)wv0.w;
    Wd[kq + 4][rl] = (double)wv1.x; Wd[kq + 5][rl] = (double)wv1.y;
    Wd[kq + 6][rl] = (double)wv1.z; Wd[kq + 7][rl] = (double)wv1.w;
    if (tid < 64) Sb[tid] = sword;
    __syncthreads();
    const unsigned int rw0 = Sb[ty * 4 + 0];
    const unsigned int rw1 = Sb[ty * 4 + 1];
    const unsigned int rw2 = Sb[ty * 4 + 2];
    const unsigned int rw3 = Sb[ty * 4 + 3];
#pragma unroll
    for (int k = 0; k < 32; ++k) {
      const double2 wa = *(const double2*)&Wd[k][tx * 4];
      const double2 wb = *(const double2*)&Wd[k][tx * 4 + 2];
      const double wv[4] = {wa.x, wa.y, wb.x, wb.y};
      const double sv[4] = {(double)((rw0 >> k) & 1u), (double)((rw1 >> k) & 1u),
                            (double)((rw2 >> k) & 1u), (double)((rw3 >> k) & 1u)};
#pragma unroll
      for (int j = 0; j < 4; ++j)
#pragma unroll
        for (int i = 0; i < 4; ++i) acc[j][i] += sv[j] * wv[i];
    }
  }
#pragma unroll
  for (int j = 0; j < 4; ++j) {
    const int b = b0 + ty * 4 + j;
#pragma unroll
    for (int i = 0; i < 4; ++i) {
      const int o = o0 + tx * 4 + i;
      if (o < kOut) out[(size_t)b * kOut + o] = (acc[j][i] >= 1.0) ? 1.0f : 0.0f;
    }
  }
}

extern "C" void kernel_launch(void* const* d_in, const int* in_sizes, int n_in,
                              void* d_out, int out_size, void* d_ws, size_t ws_size,
                              hipStream_t stream) {
  const float* x = (const float*)d_in[0];
  const float* W1 = (const float*)d_in[1];
  const float* W2 = (const float*)d_in[2];
  float* out = (float*)d_out;

  char* p = (char*)d_ws;
  signed char* w1lF = (signed char*)p;   p += kW1F;
  signed char* w2lF = (signed char*)p;   p += kW2F;
  unsigned* s1b = (unsigned*)p;          p += kS1Bytes;
  unsigned* s1T = (unsigned*)p;          p += kS1Bytes;
  uint2* xb2 = (uint2*)p;                p += kXb2Bytes;
  unsigned* list1 = (unsigned*)p;        p += (size_t)kCap1 * 4;
  unsigned* list2 = (unsigned*)p;        p += (size_t)kCap2 * 4;
  unsigned* ctrs = (unsigned*)p;         p += 256;
  const size_t need = (size_t)(p - (char*)d_ws);  // ~80 MB

  if (ws_size >= need) {
    hipMemsetAsync(ctrs, 0, 32, stream);  // ctrs[0]=fc1 cnt, ctrs[4]=fc2 cnt
    conv_w1F<<<4802, 256, 0, stream>>>(W1, w1lF);
    conv_w2F<<<784, 256, 0, stream>>>(W2, w2lF);
    pack_x2<<<50176, 256, 0, stream>>>(x, xb2);
    fc1_v12<<<dim3(16, 98), 512, 0, stream>>>(xb2, w1lF, s1b, s1T, ctrs, list1);
    fc1_correct<<<1024, 256, 0, stream>>>(x, W1, ctrs, list1, s1b, s1T);
    fc2_v7<<<dim3(128, 8), 128, 0, stream>>>(s1T, w2lF, out, ctrs + 4, list2);
    fc2_correct<<<64, 256, 0, stream>>>(s1b, W2, ctrs + 4, list2, out);
  } else {
    unsigned* s1 = (unsigned*)d_ws;
    snn_fc1<<<dim3(98, 64), 256, 0, stream>>>(x, W1, s1);
    snn_fc2<<<dim3(8, 64), 256, 0, stream>>>(s1, W2, out);
  }
}

// Round 9
// 564.877 us; speedup vs baseline: 1.2058x; 1.1726x over previous
//
#include <hip/hip_runtime.h>

// SNN 2-layer forward: s2 = (( (x@W1.T >=1) @ W2.T) >= 1)
// B=4096, IN=3136, FEAT=6272, OUT=500; x and s1 binary {0,1}.
// Exact 3-limb i8-MFMA GEMM + worst-case-safe sparse fp64 correction.
//
// Round-17: R16's dual-barrier template was worse (373us, MfmaUtil 28,
// 1 blk/CU so all waves share every phase -> pipe idle in load phases).
// 8 rounds of nulls share ONE property: a per-kt block barrier phase-locks
// all waves. fc1_v13 removes it entirely: fc2_v7's barrier-free register-
// dbuf structure, scaled: 2-wave blocks (128 thr), wave tile M=128,N=32,
// acc[4][3]=192 AGPR, zero LDS/barriers. B re-read from L2 = 56MB*32 =
// 1.8GB -> 28 B/cy/CU, half the 56 B/cy L2-return budget that sank the
// old M=64 barrier-free attempt (332us @ 7.4GB). Per step: 12 independent
// MFMA chains = 439cy pipe > ~300cy L2 latency -> self-covering; 4
// independent blocks/CU drift out of phase (m114 overlap). ~247 regs,
// launch_bounds(128,2). Grid (32,98)=3136, v6 XCD swizzle kept.

namespace {
constexpr int kB = 4096;
constexpr int kIn = 3136;        // 49 chunks of 64
constexpr int kFeat = 6272;      // 98 chunks of 64
constexpr int kFeatWords = 196;  // u32 per s1 row
constexpr int kOut = 500;
constexpr size_t kPlane1 = (size_t)kFeat * kIn;
constexpr size_t kW1F = 3 * kPlane1;                 // 59,006,976 (4802*12288)
constexpr size_t kW2F = (size_t)784 * 12288;         // 9,633,792
constexpr size_t kS1Bytes = (size_t)kB * kFeatWords * 4;  // 3,211,264 (x2)
constexpr size_t kXb2Bytes = (size_t)49 * kB * 8;    // 1,605,632
constexpr unsigned kCap1 = 1u << 20;
constexpr unsigned kCap2 = 1u << 16;
__device__ constexpr double kTau1 = 7.4769e-4;       // > 3136*2^-22
__device__ constexpr double kTau2 = 1.4955e-3;       // > 6272*2^-22
}  // namespace

typedef int v4i __attribute__((ext_vector_type(4)));
typedef int v16i __attribute__((ext_vector_type(16)));

// 16 bits -> 16 i8 (byte i = bit i)
__device__ __forceinline__ v4i expand16(unsigned b) {
  unsigned u0 = (((b      ) & 0xFu) * 0x204081u) & 0x01010101u;
  unsigned u1 = (((b >> 4 ) & 0xFu) * 0x204081u) & 0x01010101u;
  unsigned u2 = (((b >> 8 ) & 0xFu) * 0x204081u) & 0x01010101u;
  unsigned u3 = (((b >> 12) & 0xFu) * 0x204081u) & 0x01010101u;
  return (v4i){(int)u0, (int)u1, (int)u2, (int)u3};
}

// exact 3-digit signed base-128 split; |w - sum| <= 2^-22
__device__ __forceinline__ void split3(float w, signed char* d) {
  float c = rintf(w * 128.f);
  d[0] = (signed char)(int)c;
  float r = fmaf(c, -7.8125e-03f, w);
  c = rintf(r * 16384.f);
  d[1] = (signed char)(int)c;
  r = fmaf(c, -6.103515625e-05f, r);
  c = rintf(r * 2097152.f);
  d[2] = (signed char)(int)c;
}

// ---------------------------------------------------------------------------
// W1 -> fragment-major limbs: slot(fb,kt,j,g) = 1KB of 64 feats x 16 k-bytes.
// ---------------------------------------------------------------------------
__global__ __launch_bounds__(256) void conv_w1F(const float* __restrict__ W,
                                                signed char* __restrict__ F) {
  const int bx = blockIdx.x;               // fb*49 + kt, < 4802
  const int fb = bx / 49;
  const int kt = bx % 49;
  const int f = threadIdx.x & 63;
  const int g = threadIdx.x >> 6;
  const float* src = W + (size_t)(fb * 64 + f) * kIn + kt * 64 + g * 16;
  union { signed char c[16]; int4 v; } o[3];
#pragma unroll
  for (int q = 0; q < 4; ++q) {
    const float4 w = *(const float4*)(src + q * 4);
    signed char d[4][3];
    split3(w.x, d[0]); split3(w.y, d[1]); split3(w.z, d[2]); split3(w.w, d[3]);
#pragma unroll
    for (int e = 0; e < 4; ++e)
#pragma unroll
      for (int j = 0; j < 3; ++j) o[j].c[q * 4 + e] = d[e][j];
  }
#pragma unroll
  for (int j = 0; j < 3; ++j)
    *(int4*)(F + ((size_t)bx * 3 + j) * 4096 + g * 1024 + f * 16) = o[j].v;
}

// W2 (padded to 512 rows) -> fragment-major limbs, slots (fb<8, kt<98, j, g)
__global__ __launch_bounds__(256) void conv_w2F(const float* __restrict__ W,
                                                signed char* __restrict__ F) {
  const int bx = blockIdx.x;               // fb*98 + kt, < 784
  const int fb = bx / 98;
  const int kt = bx % 98;
  const int f = threadIdx.x & 63;
  const int g = threadIdx.x >> 6;
  const int feat = fb * 64 + f;
  union { signed char c[16]; int4 v; } o[3];
#pragma unroll
  for (int q = 0; q < 4; ++q) {
    float4 w = {0.f, 0.f, 0.f, 0.f};
    if (feat < kOut)
      w = *(const float4*)(W + (size_t)feat * kFeat + kt * 64 + g * 16 + q * 4);
    signed char d[4][3];
    split3(w.x, d[0]); split3(w.y, d[1]); split3(w.z, d[2]); split3(w.w, d[3]);
#pragma unroll
    for (int e = 0; e < 4; ++e)
#pragma unroll
      for (int j = 0; j < 3; ++j) o[j].c[q * 4 + e] = d[e][j];
  }
#pragma unroll
  for (int j = 0; j < 3; ++j)
    *(int4*)(F + ((size_t)bx * 3 + j) * 4096 + g * 1024 + f * 16) = o[j].v;
}

// x -> transposed packed bits: xb2[kt*4096 + b]
__global__ __launch_bounds__(256) void pack_x2(const float* __restrict__ X,
                                               uint2* __restrict__ xb2) {
  const int wid = (blockIdx.x * 256 + threadIdx.x) >> 6;  // < 200,704
  const int lane = threadIdx.x & 63;
  const int b = wid / 49;
  const int g = wid % 49;
  const float v = X[(size_t)b * kIn + g * 64 + lane];
  const unsigned long long bal = __ballot(v != 0.f);
  if (lane == 0) xb2[(size_t)g * kB + b] = make_uint2((unsigned)bal, (unsigned)(bal >> 32));
}

// ---------------------------------------------------------------------------
// FC1 v13: barrier-free register-dbuf (fc2_v7 structure). 128 thr = 2 waves;
// wave wvN covers feats bx*64 + wvN*32 + [0,32), rows bM + [0,128)
// (4 subtiles of 32). acc[4][3] (192 AGPR). Per (kt,kk) step: 3 B dwordx4
// from L2 (dbuf'd), 4 expand16, 12 independent-chain MFMA. A (bit-words)
// prefetched 1 kt ahead. No LDS, no barriers -> 4 independent blocks/CU
// drift out of phase; MFMA pipe fed from whichever wave is in compute.
// Grid (32, 98); XCD swizzle 3136 = 8*392 (same-bx blocks on one XCD).
// ---------------------------------------------------------------------------
__global__ __launch_bounds__(128, 2) void fc1_v13(
    const uint2* __restrict__ xb2, const signed char* __restrict__ w1lF,
    unsigned* __restrict__ s1b, unsigned* __restrict__ s1T,
    unsigned* __restrict__ cnt, unsigned* __restrict__ list) {
  const int tid = threadIdx.x;
  const int lane = tid & 63;
  const int ln31 = lane & 31;
  const int half = lane >> 5;
  const int wvN = tid >> 6;      // 0..1 (feat half of the 64-feat panel)

  // XCD swizzle: 3136 = 8*392 (bijective); same-bx blocks cluster per XCD.
  const int lin = blockIdx.x + 32 * blockIdx.y;     // 0..3135
  const int sw = (lin & 7) * 392 + (lin >> 3);
  const int bx = sw >> 5;        // N-panel (64 feats), 0..97
  const int bM = (sw & 31) * 128;

  const signed char* const gb = w1lF + (size_t)bx * 49 * 12288;
  const unsigned hsel = half * 1024u + (wvN * 32 + ln31) * 16u;
  const uint2* const aptr = xb2 + bM + ln31;

  v16i acc[4][3] = {};
  v4i b0[3], b1[3];
  uint2 aC[4], aN[4];

#define FC1_LB(KT, KK, BF)                                                    \
  {                                                                           \
    const signed char* bp_ = gb + (size_t)(KT) * 12288 + (KK) * 2048 + hsel;  \
    (BF)[0] = *(const v4i*)(bp_);                                             \
    (BF)[1] = *(const v4i*)(bp_ + 4096);                                      \
    (BF)[2] = *(const v4i*)(bp_ + 8192);                                      \
  }
#define FC1_LA(KT, AR)                                                        \
  {                                                                           \
    _Pragma("unroll")                                                         \
    for (int s = 0; s < 4; ++s) (AR)[s] = aptr[(size_t)(KT) * kB + s * 32];   \
  }
#define FC1_COMP(BF, AW, SEL)                                                 \
  {                                                                           \
    _Pragma("unroll")                                                         \
    for (int s = 0; s < 4; ++s) {                                             \
      const unsigned w_ = (SEL) ? (AW)[s].y : (AW)[s].x;                      \
      const v4i a_ = expand16((w_ >> (half * 16)) & 0xFFFFu);                 \
      acc[s][0] = __builtin_amdgcn_mfma_i32_32x32x32_i8(a_, (BF)[0], acc[s][0], 0, 0, 0); \
      acc[s][1] = __builtin_amdgcn_mfma_i32_32x32x32_i8(a_, (BF)[1], acc[s][1], 0, 0, 0); \
      acc[s][2] = __builtin_amdgcn_mfma_i32_32x32x32_i8(a_, (BF)[2], acc[s][2], 0, 0, 0); \
    }                                                                         \
  }

  FC1_LB(0, 0, b0);
  FC1_LA(0, aC);
#pragma unroll
  for (int s = 0; s < 4; ++s) aN[s] = aC[s];

  for (int kt = 0; kt < 49; ++kt) {
    FC1_LB(kt, 1, b1);               // prefetch kk=1 of current kt
    if (kt < 48) FC1_LA(kt + 1, aN); // prefetch next kt's A words
    FC1_COMP(b0, aC, 0);
    if (kt < 48) FC1_LB(kt + 1, 0, b0);  // prefetch kk=0 of next kt
    FC1_COMP(b1, aC, 1);
#pragma unroll
    for (int s = 0; s < 4; ++s) aC[s] = aN[s];
  }
#undef FC1_LB
#undef FC1_LA
#undef FC1_COMP

  const double s7 = 0.0078125;
  const int word = bx * 2 + wvN;
  const int fcol = word * 32 + ln31;
#pragma unroll
  for (int sub = 0; sub < 4; ++sub) {
#pragma unroll
    for (int t = 0; t < 16; ++t) {
      double v = (double)acc[sub][2][t];
      v = v * s7 + (double)acc[sub][1][t];
      v = v * s7 + (double)acc[sub][0][t];
      v = v * s7;
      const unsigned long long bal = __ballot(v >= 1.0);
      const int mrow = bM + sub * 32 + (t & 3) + 8 * (t >> 2);
      if (lane == 0) {
        s1b[(size_t)mrow * kFeatWords + word] = (unsigned)bal;
        s1T[(size_t)word * kB + mrow] = (unsigned)bal;
      }
      if (lane == 32) {
        s1b[(size_t)(mrow + 4) * kFeatWords + word] = (unsigned)(bal >> 32);
        s1T[(size_t)word * kB + mrow + 4] = (unsigned)(bal >> 32);
      }
      if (fabs(v - 1.0) <= kTau1) {
        const unsigned idx = atomicAdd(cnt, 1u);
        if (idx < kCap1) list[idx] = ((unsigned)(mrow + 4 * half) << 13) | (unsigned)fcol;
      }
    }
  }
}

// exact fp64 recompute of flagged FC1 dots; fixes s1b AND s1T
__global__ __launch_bounds__(256) void fc1_correct(
    const float* __restrict__ x, const float* __restrict__ W1,
    const unsigned* __restrict__ cnt, const unsigned* __restrict__ list,
    unsigned* __restrict__ s1b, unsigned* __restrict__ s1T) {
  const unsigned n = min(cnt[0], kCap1);
  const int lane = threadIdx.x & 63;
  const int wid = (blockIdx.x * 256 + threadIdx.x) >> 6;
  const int nw = (gridDim.x * 256) >> 6;
  for (unsigned i = wid; i < n; i += nw) {
    const unsigned u = list[i];
    const int b = (int)(u >> 13);
    const int f = (int)(u & 8191u);
    double s = 0.0;
    for (int k = lane; k < kIn; k += 64)
      s = fma((double)x[(size_t)b * kIn + k], (double)W1[(size_t)f * kIn + k], s);
#pragma unroll
    for (int off = 32; off > 0; off >>= 1) s += __shfl_down(s, off);
    if (lane == 0) {
      const unsigned mask = 1u << (f & 31);
      unsigned* p1 = s1b + (size_t)b * kFeatWords + (f >> 5);
      unsigned* p2 = s1T + (size_t)(f >> 5) * kB + b;
      if (s >= 1.0) { atomicOr(p1, mask); atomicOr(p2, mask); }
      else          { atomicAnd(p1, ~mask); atomicAnd(p2, ~mask); }
    }
  }
}

// ---------------------------------------------------------------------------
// FC2 v7: barrier-free register-dbuf, 2-wave blocks (tile 32 rows x 64 outs),
// grid (128, 8) = 1024 blocks -> 8 blocks/CU for latency interleave. A bits
// from s1T, B frags dwordx4 from L2. XCD swizzle: each XCD owns one N-panel.
// ---------------------------------------------------------------------------
__global__ __launch_bounds__(128, 4) void fc2_v7(
    const unsigned* __restrict__ s1T, const signed char* __restrict__ w2lF,
    float* __restrict__ out, unsigned* __restrict__ cnt,
    unsigned* __restrict__ list) {
  const int tid = threadIdx.x;
  const int lane = tid & 63;
  const int ln31 = lane & 31;
  const int half = lane >> 5;
  const int wvN = tid >> 6;    // 0..1 (waveN)

  const int lin = blockIdx.x + 128 * blockIdx.y;    // 0..1023
  const int sw = ((lin & 7) << 7) + (lin >> 3);     // 1024 = 8*128
  const int bx = sw >> 7;      // N-block (64 outs), 0..7
  const int bM = (sw & 127) * 32;

  const unsigned* const aptr = s1T + bM + ln31;
  const int fl = wvN * 32 + ln31;
  const signed char* const bbase =
      w2lF + (size_t)(bx * 98) * 12288 + half * 1024u + fl * 16u;

  v16i acc[3] = {};
  v4i b0[6], b1[6];
  uint2 a0, a1;

#define LOAD_TILE(nk, bf, ab)                                   \
  {                                                             \
    const signed char* bp = bbase + (size_t)(nk) * 12288;       \
    bf[0] = *(const v4i*)(bp);                                  \
    bf[1] = *(const v4i*)(bp + 2048);                           \
    bf[2] = *(const v4i*)(bp + 4096);                           \
    bf[3] = *(const v4i*)(bp + 6144);                           \
    bf[4] = *(const v4i*)(bp + 8192);                           \
    bf[5] = *(const v4i*)(bp + 10240);                          \
    (ab).x = aptr[(size_t)((nk) * 2) * kB];                     \
    (ab).y = aptr[(size_t)((nk) * 2 + 1) * kB];                 \
  }
#define COMPUTE_TILE(bf, ab)                                                    \
  {                                                                             \
    _Pragma("unroll")                                                           \
    for (int kk = 0; kk < 2; ++kk) {                                            \
      const unsigned word = kk ? (ab).y : (ab).x;                               \
      const v4i a = expand16((word >> (half * 16)) & 0xFFFFu);                  \
      acc[0] = __builtin_amdgcn_mfma_i32_32x32x32_i8(a, bf[kk], acc[0], 0,0,0); \
      acc[1] = __builtin_amdgcn_mfma_i32_32x32x32_i8(a, bf[2+kk], acc[1],0,0,0);\
      acc[2] = __builtin_amdgcn_mfma_i32_32x32x32_i8(a, bf[4+kk], acc[2],0,0,0);\
    }                                                                           \
  }

  LOAD_TILE(0, b0, a0);
  for (int kt = 0; kt + 2 <= 98; kt += 2) {
    LOAD_TILE(kt + 1, b1, a1);
    COMPUTE_TILE(b0, a0);
    const int nk2 = (kt + 2 < 98) ? kt + 2 : 97;  // last reload harmless
    LOAD_TILE(nk2, b0, a0);
    COMPUTE_TILE(b1, a1);
  }

  const double s7 = 0.0078125;
  const int o = bx * 64 + wvN * 32 + ln31;
#pragma unroll
  for (int t = 0; t < 16; ++t) {
    double v = (double)acc[2][t];
    v = v * s7 + (double)acc[1][t];
    v = v * s7 + (double)acc[0][t];
    v = v * s7;
    const int b = bM + (t & 3) + 8 * (t >> 2) + 4 * half;
    if (o < kOut) {
      out[(size_t)b * kOut + o] = (v >= 1.0) ? 1.0f : 0.0f;
      if (fabs(v - 1.0) <= kTau2) {
        const unsigned idx = atomicAdd(cnt, 1u);
        if (idx < kCap2) list[idx] = ((unsigned)b << 13) | (unsigned)o;
      }
    }
  }
#undef LOAD_TILE
#undef COMPUTE_TILE
}

// exact fp64 recompute of flagged FC2 dots (reads row-major s1b)
__global__ __launch_bounds__(256) void fc2_correct(
    const unsigned* __restrict__ s1b, const float* __restrict__ W2,
    const unsigned* __restrict__ cnt, const unsigned* __restrict__ list,
    float* __restrict__ out) {
  const unsigned n = min(cnt[0], kCap2);
  const int lane = threadIdx.x & 63;
  const int wid = (blockIdx.x * 256 + threadIdx.x) >> 6;
  const int nw = (gridDim.x * 256) >> 6;
  for (unsigned i = wid; i < n; i += nw) {
    const unsigned u = list[i];
    const int b = (int)(u >> 13);
    const int o = (int)(u & 8191u);
    double s = 0.0;
    for (int k = lane; k < kFeat; k += 64) {
      const unsigned w = s1b[(size_t)b * kFeatWords + (k >> 5)];
      if ((w >> (k & 31)) & 1u) s += (double)W2[(size_t)o * kFeat + k];
    }
#pragma unroll
    for (int off = 32; off > 0; off >>= 1) s += __shfl_down(s, off);
    if (lane == 0) out[(size_t)b * kOut + o] = (s >= 1.0) ? 1.0f : 0.0f;
  }
}

// ---------------------------------------------------------------------------
// fp64 fallback (round-1 validated) — only if ws too small.
// ---------------------------------------------------------------------------
__global__ __launch_bounds__(256) void snn_fc1(const float* __restrict__ x,
                                               const float* __restrict__ W1,
                                               unsigned int* __restrict__ s1bits) {
  __shared__ double Xd[32][66];
  __shared__ double Wd[32][66];
  __shared__ unsigned int spikes[64][2];
  const int tid = threadIdx.x;
  const int tx = tid & 15;
  const int ty = tid >> 4;
  const int b0 = blockIdx.y * 64;
  const int f0 = blockIdx.x * 64;
  if (tid < 128) spikes[tid >> 1][tid & 1] = 0u;
  double acc[4][4];
#pragma unroll
  for (int j = 0; j < 4; ++j)
#pragma unroll
    for (int i = 0; i < 4; ++i) acc[j][i] = 0.0;
  const int rl = tid >> 2;
  const int kq = (tid & 3) * 8;
  const float* xrow = x + (size_t)(b0 + rl) * kIn + kq;
  const float* wrow = W1 + (size_t)(f0 + rl) * kIn + kq;
  for (int kc = 0; kc < kIn; kc += 32) {
    const float4 xv0 = *(const float4*)(xrow + kc);
    const float4 xv1 = *(const float4*)(xrow + kc + 4);
    const float4 wv0 = *(const float4*)(wrow + kc);
    const float4 wv1 = *(const float4*)(wrow + kc + 4);
    __syncthreads();
    Xd[kq + 0][rl] = (double)xv0.x; Xd[kq + 1][rl] = (double)xv0.y;
    Xd[kq + 2][rl] = (double)xv0.z; Xd[kq + 3][rl] = (double)xv0.w;
    Xd[kq + 4][rl] = (double)xv1.x; Xd[kq + 5][rl] = (double)xv1.y;
    Xd[kq + 6][rl] = (double)xv1.z; Xd[kq + 7][rl] = (double)xv1.w;
    Wd[kq + 0][rl] = (double)wv0.x; Wd[kq + 1][rl] = (double)wv0.y;
    Wd[kq + 2][rl] = (double)wv0.z; Wd[kq + 3][rl] = (double)wv0.w;
    Wd[kq + 4][rl] = (double)wv1.x; Wd[kq + 5][rl] = (double)wv1.y;
    Wd[kq + 6][rl] = (double)wv1.z; Wd[kq + 7][rl] = (double)wv1.w;
    __syncthreads();
#pragma unroll
    for (int k = 0; k < 32; ++k) {
      const double2 xa = *(const double2*)&Xd[k][ty * 4];
      const double2 xb = *(const double2*)&Xd[k][ty * 4 + 2];
      const double2 wa = *(const double2*)&Wd[k][tx * 4];
      const double2 wb = *(const double2*)&Wd[k][tx * 4 + 2];
      const double xv[4] = {xa.x, xa.y, xb.x, xb.y};
      const double wv[4] = {wa.x, wa.y, wb.x, wb.y};
#pragma unroll
      for (int j = 0; j < 4; ++j)
#pragma unroll
        for (int i = 0; i < 4; ++i) acc[j][i] += xv[j] * wv[i];
    }
  }
  __syncthreads();
#pragma unroll
  for (int j = 0; j < 4; ++j) {
    unsigned int nib = 0u;
#pragma unroll
    for (int i = 0; i < 4; ++i) nib |= (acc[j][i] >= 1.0 ? 1u : 0u) << i;
    atomicOr(&spikes[ty * 4 + j][tx >> 3], nib << ((tx * 4) & 31));
  }
  __syncthreads();
  if (tid < 128) {
    const int r = tid >> 1;
    const int w = tid & 1;
    s1bits[(size_t)(b0 + r) * kFeatWords + (f0 >> 5) + w] = spikes[r][w];
  }
}

__global__ __launch_bounds__(256) void snn_fc2(const unsigned int* __restrict__ s1bits,
                                               const float* __restrict__ W2,
                                               float* __restrict__ out) {
  __shared__ double Wd[32][66];
  __shared__ unsigned int Sb[64];
  const int tid = threadIdx.x;
  const int tx = tid & 15;
  const int ty = tid >> 4;
  const int b0 = blockIdx.y * 64;
  const int o0 = blockIdx.x * 64;
  double acc[4][4];
#pragma unroll
  for (int j = 0; j < 4; ++j)
#pragma unroll
    for (int i = 0; i < 4; ++i) acc[j][i] = 0.0;
  const int rl = tid >> 2;
  const int kq = (tid & 3) * 8;
  int orow = o0 + rl;
  if (orow >= kOut) orow = kOut - 1;
  const float* wrow = W2 + (size_t)orow * kFeat + kq;
  for (int kc = 0; kc < kFeat; kc += 32) {
    const float4 wv0 = *(const float4*)(wrow + kc);
    const float4 wv1 = *(const float4*)(wrow + kc + 4);
    unsigned int sword = 0u;
    if (tid < 64) sword = s1bits[(size_t)(b0 + tid) * kFeatWords + (kc >> 5)];
    __syncthreads();
    Wd[kq + 0][rl] = (double)wv0.x; Wd[kq + 1][rl] = (double)wv0.y;
    Wd[kq + 2][rl] = (double)wv0.z; Wd[kq + 3][rl] = (double)wv0.w;
    Wd[kq + 4][rl] = (double)wv1.x; Wd[kq + 5][rl] = (double)wv1.y;
    Wd[kq + 6][rl] = (double)wv1.z; Wd[kq + 7][rl] = (double)wv1.w;
    if (tid < 64) Sb[tid] = sword;
    __syncthreads();
    const unsigned int rw0 = Sb[ty * 4 + 0];
    const unsigned int rw1 = Sb[ty * 4 + 1];
    const unsigned int rw2 = Sb[ty * 4 + 2];
    const unsigned int rw3 = Sb[ty * 4 + 3];
#pragma unroll
    for (int k = 0; k < 32; ++k) {
      const double2 wa = *(const double2*)&Wd[k][tx * 4];
      const double2 wb = *(const double2*)&Wd[k][tx * 4 + 2];
      const double wv[4] = {wa.x, wa.y, wb.x, wb.y};
      const double sv[4] = {(double)((rw0 >> k) & 1u), (double)((rw1 >> k) & 1u),
                            (double)((rw2 >> k) & 1u), (double)((rw3 >> k) & 1u)};
#pragma unroll
      for (int j = 0; j < 4; ++j)
#pragma unroll
        for (int i = 0; i < 4; ++i) acc[j][i] += sv[j] * wv[i];
    }
  }
#pragma unroll
  for (int j = 0; j < 4; ++j) {
    const int b = b0 + ty * 4 + j;
#pragma unroll
    for (int i = 0; i < 4; ++i) {
      const int o = o0 + tx * 4 + i;
      if (o < kOut) out[(size_t)b * kOut + o] = (acc[j][i] >= 1.0) ? 1.0f : 0.0f;
    }
  }
}

extern "C" void kernel_launch(void* const* d_in, const int* in_sizes, int n_in,
                              void* d_out, int out_size, void* d_ws, size_t ws_size,
                              hipStream_t stream) {
  const float* x = (const float*)d_in[0];
  const float* W1 = (const float*)d_in[1];
  const float* W2 = (const float*)d_in[2];
  float* out = (float*)d_out;

  char* p = (char*)d_ws;
  signed char* w1lF = (signed char*)p;   p += kW1F;
  signed char* w2lF = (signed char*)p;   p += kW2F;
  unsigned* s1b = (unsigned*)p;          p += kS1Bytes;
  unsigned* s1T = (unsigned*)p;          p += kS1Bytes;
  uint2* xb2 = (uint2*)p;                p += kXb2Bytes;
  unsigned* list1 = (unsigned*)p;        p += (size_t)kCap1 * 4;
  unsigned* list2 = (unsigned*)p;        p += (size_t)kCap2 * 4;
  unsigned* ctrs = (unsigned*)p;         p += 256;
  const size_t need = (size_t)(p - (char*)d_ws);  // ~80 MB

  if (ws_size >= need) {
    hipMemsetAsync(ctrs, 0, 32, stream);  // ctrs[0]=fc1 cnt, ctrs[4]=fc2 cnt
    conv_w1F<<<4802, 256, 0, stream>>>(W1, w1lF);
    conv_w2F<<<784, 256, 0, stream>>>(W2, w2lF);
    pack_x2<<<50176, 256, 0, stream>>>(x, xb2);
    fc1_v13<<<dim3(32, 98), 128, 0, stream>>>(xb2, w1lF, s1b, s1T, ctrs, list1);
    fc1_correct<<<1024, 256, 0, stream>>>(x, W1, ctrs, list1, s1b, s1T);
    fc2_v7<<<dim3(128, 8), 128, 0, stream>>>(s1T, w2lF, out, ctrs + 4, list2);
    fc2_correct<<<64, 256, 0, stream>>>(s1b, W2, ctrs + 4, list2, out);
  } else {
    unsigned* s1 = (unsigned*)d_ws;
    snn_fc1<<<dim3(98, 64), 256, 0, stream>>>(x, W1, s1);
    snn_fc2<<<dim3(8, 64), 256, 0, stream>>>(s1, W2, out);
  }
}